// Round 8
// baseline (215.913 us; speedup 1.0000x reference)
//
#include <hip/hip_runtime.h>
#include <math.h>
#include <stdint.h>

typedef _Float16 half8 __attribute__((ext_vector_type(8)));
typedef float floatx4 __attribute__((ext_vector_type(4)));

#define NTOK 16384
#define DIM  2048
#define NEXP 64
#define TPW  16                    // tokens per wave (one 16x16x32 M-tile)
#define KSPLIT 4                   // K-slices per token group
#define KSLICE (DIM / KSPLIT)      // 512 dims per wave
#define NSTEP  (KSLICE / 32)       // 16 k-steps per wave
#define NBLK (NTOK / TPW)          // 1024 blocks, 256 thr = 4 waves (the 4 K-slices)
#define WSW_H8 16384               // half8 slots per split (64 ksteps x 4 tg x 64 lanes)
#define WSW_BYTES (2 * WSW_H8 * 16)

// ---- prep: split W (fp32) into f16 hi + scaled-lo (2^11), B-fragment order:
// slot(sg,tg,lane) = (sg*4+tg)*64+lane holds W[tg*16+(lane&15)][sg*32+(lane>>4)*8 + 0..7]
__global__ void wprep_kernel(const float* __restrict__ W, _Float16* __restrict__ wsw) {
    const int id   = blockIdx.x * blockDim.x + threadIdx.x; // 0..16383
    const int lane = id & 63;
    const int tg   = (id >> 6) & 3;
    const int sg   = id >> 8;                               // 0..63
    const int e    = tg * 16 + (lane & 15);
    const int k    = sg * 32 + (lane >> 4) * 8;
    const float* src = W + (size_t)e * DIM + k;
    half8 h, l;
#pragma unroll
    for (int j = 0; j < 8; j++) {
        const float v  = src[j];
        const _Float16 hh = (_Float16)v;
        h[j] = hh;
        l[j] = (_Float16)((v - (float)hh) * 2048.0f);
    }
    const size_t slot = (size_t)(sg * 4 + tg) * 64 + lane;
    ((half8*)wsw)[slot]          = h;
    ((half8*)wsw)[WSW_H8 + slot] = l;
}

__device__ __forceinline__ void split_a(const float4& v0, const float4& v1,
                                        half8& hi, half8& lo) {
    const float av[8] = {v0.x, v0.y, v0.z, v0.w, v1.x, v1.y, v1.z, v1.w};
#pragma unroll
    for (int j = 0; j < 8; j++) {
        const _Float16 hh = (_Float16)av[j];
        hi[j] = hh;
        lo[j] = (_Float16)((av[j] - (float)hh) * 2048.0f);
    }
}

template <bool USE_WS>
__global__ __launch_bounds__(256, 4)   // cap VGPR at 128: 4 waves/SIMD, grid fully resident
void gating_lean_kernel(const float* __restrict__ x, const float* __restrict__ W,
                        const _Float16* __restrict__ wsw, const float* __restrict__ bias,
                        float* __restrict__ out)
{
    __shared__ __align__(16) float part[KSPLIT * TPW * NEXP];   // 16 KB

    const int tid  = threadIdx.x;
    const int lane = tid & 63;
    const int w    = tid >> 6;          // 0..3 = K-slice owner
    const int col  = lane & 15;
    const int quad = lane >> 4;
    const int tok0 = blockIdx.x * TPW;

    floatx4 accm[4] = {{0,0,0,0},{0,0,0,0},{0,0,0,0},{0,0,0,0}};
    floatx4 accl[4] = {{0,0,0,0},{0,0,0,0},{0,0,0,0},{0,0,0,0}};

    // A: lane holds A[m=col][k=quad*8 + 0..7] of token tok0+col, K-slice w
    const float* xrow = x + (size_t)(tok0 + col) * DIM + w * KSLICE + quad * 8;
    const half8* bb   = (const half8*)wsw + lane;

    // ---- barrier-free K-loop: 16 steps of 32 dims; small live set, no LDS.
#pragma unroll 2
    for (int s = 0; s < NSTEP; ++s) {
        const float4 v0 = *(const float4*)(xrow + s * 32);
        const float4 v1 = *(const float4*)(xrow + s * 32 + 4);
        half8 ah, al;
        split_a(v0, v1, ah, al);

        const int sg = w * NSTEP + s;   // global 32-dim k-step index 0..63
#pragma unroll
        for (int tg = 0; tg < 4; ++tg) {
            half8 bh, bl;
            if constexpr (USE_WS) {
                const size_t fi = (size_t)(sg * 4 + tg) * 64;
                bh = bb[fi];
                bl = bb[WSW_H8 + fi];
            } else {
                const float* wr = W + (size_t)(tg * 16 + col) * DIM + sg * 32 + quad * 8;
                split_a(*(const float4*)wr, *(const float4*)(wr + 4), bh, bl);
            }
            accm[tg] = __builtin_amdgcn_mfma_f32_16x16x32_f16(ah, bh, accm[tg], 0, 0, 0);
            accl[tg] = __builtin_amdgcn_mfma_f32_16x16x32_f16(ah, bl, accl[tg], 0, 0, 0);
            accl[tg] = __builtin_amdgcn_mfma_f32_16x16x32_f16(al, bh, accl[tg], 0, 0, 0);
        }
    }

    // ---- per-wave partials -> LDS.  C/D: token m = quad*4+r, expert n = tg*16 + (lane&15)
    const float inv = 1.0f / 2048.0f;
#pragma unroll
    for (int tg = 0; tg < 4; ++tg)
#pragma unroll
        for (int r = 0; r < 4; ++r)
            part[w * (TPW * NEXP) + (quad * 4 + r) * NEXP + tg * 16 + col]
                = accm[tg][r] + accl[tg][r] * inv;
    __syncthreads();

    // ---- cross-wave K-reduction: each thread owns 4 consecutive (tok,exp) slots
    floatx4 red = {0, 0, 0, 0};
#pragma unroll
    for (int w2 = 0; w2 < KSPLIT; ++w2)
        red += *(const floatx4*)(part + w2 * (TPW * NEXP) + tid * 4);
    const floatx4 bv = *(const floatx4*)(bias + ((tid * 4) & 63));
    __syncthreads();                 // all reads done before aliasing fin onto part

    float* fin = part;               // [16 tok][65] stride-65 (conflict-free scan)
#pragma unroll
    for (int i = 0; i < 4; ++i) {
        const int p = tid * 4 + i;
        fin[(p >> 6) * 65 + (p & 63)] = red[i] + bv[i];
    }
    __syncthreads();

    // ---- top-2 + softmax: one thread per token
    if (tid < TPW) {
        const int t = tid;
        float v0 = -INFINITY, v1 = -INFINITY;
        int   i0 = 0, i1 = 0;
        for (int e = 0; e < NEXP; e++) {
            const float v = fin[t * 65 + e];
            if (v > v0) { v1 = v0; i1 = i0; v0 = v; i0 = e; }
            else if (v > v1) { v1 = v; i1 = e; }
        }
        const float e1 = expf(v1 - v0);   // v1 <= v0: stable
        const float sden = 1.f + e1;
        const int   g  = tok0 + t;
        out[2 * g + 0] = 1.f / sden;
        out[2 * g + 1] = e1 / sden;
        out[2 * NTOK + 2 * g + 0] = (float)i0;
        out[2 * NTOK + 2 * g + 1] = (float)i1;
    }
}

extern "C" void kernel_launch(void* const* d_in, const int* in_sizes, int n_in,
                              void* d_out, int out_size, void* d_ws, size_t ws_size,
                              hipStream_t stream) {
    const float* x    = (const float*)d_in[0];
    const float* W    = (const float*)d_in[1];
    const float* bias = (const float*)d_in[2];
    float*       out  = (float*)d_out;
    _Float16*    wsw  = (_Float16*)d_ws;

    if (ws_size >= (size_t)WSW_BYTES) {
        hipLaunchKernelGGL(wprep_kernel, dim3(64), dim3(256), 0, stream, (const float*)d_in[1], wsw);
        hipLaunchKernelGGL((gating_lean_kernel<true>), dim3(NBLK), dim3(256), 0, stream,
                           x, W, wsw, bias, out);
    } else {
        hipLaunchKernelGGL((gating_lean_kernel<false>), dim3(NBLK), dim3(256), 0, stream,
                           x, W, wsw, bias, out);
    }
}